// Round 6
// baseline (217.740 us; speedup 1.0000x reference)
//
#include <hip/hip_runtime.h>

#define UNITS 20

typedef __attribute__((ext_vector_type(8))) short short8;
typedef __attribute__((ext_vector_type(4))) float floatx4;
typedef __attribute__((ext_vector_type(2))) unsigned int u32x2;
typedef __attribute__((ext_vector_type(4))) unsigned int u32x4;
typedef unsigned int u32;
typedef unsigned short u16;

__device__ __forceinline__ float rcpf_fast(float x) { return __builtin_amdgcn_rcpf(x); }
__device__ __forceinline__ float sigmoidf_fast(float x) { return rcpf_fast(1.0f + __expf(-x)); }
__device__ __forceinline__ float tanhf_fast(float x) { return 1.0f - 2.0f * rcpf_fast(1.0f + __expf(2.0f * x)); }

__device__ __forceinline__ u32 f2bf(float f) {
  u32 u = __builtin_bit_cast(u32, f);
  u += 0x7fffu + ((u >> 16) & 1u);   // RNE
  return u >> 16;
}
// packed f32->bf16 (RNE): lo -> D[15:0], hi -> D[31:16]
__device__ __forceinline__ u32 cvtpk(float lo, float hi) {
  u32 r;
  asm("v_cvt_pk_bf16_f32 %0, %1, %2" : "=v"(r) : "v"(lo), "v"(hi));
  return r;
}

// ---------------------------------------------------------------------------
// Prep (unchanged): pack A-operand fragments.
//  gates^T = Wcat . Z^T, permuted rows -> acc[t][reg] = gate[reg*20+q*5+t].
//  lateral^T with sigma-permuted K (k=q*8+j holds W_lat col q*5+j, j<5) so
//  the lateral B-operand is lane-local in the main kernel.
// ---------------------------------------------------------------------------
__global__ void prep_kernel(const float* __restrict__ W_ih, const float* __restrict__ W_hh,
                            const float* __restrict__ b_ih, const float* __restrict__ b_hh,
                            const float* __restrict__ W_lat,
                            u16* __restrict__ fragsG, u16* __restrict__ fragsL,
                            float4* __restrict__ bias4) {
  int tid = threadIdx.x;
  for (int e = tid; e < 768; e += 256) {   // 10 gate frags + 2 lateral frags
    int fi = e >> 6, lane = e & 63;
    int r = lane & 15, q = lane >> 4;
    short8 v8;
    if (fi < 10) {
      int t = fi >> 1, cc = fi & 1;
      int gr = (r & 3) * 20 + (r >> 2) * 5 + t;   // permuted gate row
#pragma unroll
      for (int j = 0; j < 8; ++j) {
        int k = cc * 32 + q * 8 + j;
        float v = 0.0f;
        if (k < 20) v = W_ih[gr * UNITS + k];
        else if (k < 40) v = W_hh[gr * UNITS + (k - 20)];
        v8[j] = (short)f2bf(v);
      }
      *(short8*)(fragsG + (size_t)e * 8) = v8;
    } else {
      int t = fi - 10;
      int vr = t * 16 + r;
#pragma unroll
      for (int j = 0; j < 8; ++j) {
        float v = (vr < 20 && j < 5) ? W_lat[vr * UNITS + q * 5 + j] : 0.0f;
        v8[j] = (short)f2bf(v);
      }
      *(short8*)(fragsL + (size_t)(t * 64 + lane) * 8) = v8;
    }
  }
  if (tid < 20)
    bias4[tid] = make_float4(b_ih[tid] + b_hh[tid],
                             b_ih[20 + tid] + b_hh[20 + tid],
                             b_ih[40 + tid] + b_hh[40 + tid],
                             b_ih[60 + tid] + b_hh[60 + tid]);
}

// ---------------------------------------------------------------------------
// Main: round-2 structure + DEPTH-2 software pipeline (the single change).
// Two register load-sets rotate over grid-stride passes: while pass p
// computes, loads for p+1 AND p+2 are in flight (~7.7 KB/wave vs 3.8).
// Plain (cached) stores; wave-private LDS staging; no in-loop barriers.
// ---------------------------------------------------------------------------
__global__ __launch_bounds__(256, 4) void stn_main(
    const float* __restrict__ x, const float* __restrict__ h, const float* __restrict__ c,
    const u16* __restrict__ fragsG, const u16* __restrict__ fragsL,
    const float4* __restrict__ bias4, float* __restrict__ out, int B) {
  __shared__ unsigned char smem[20480];

  // stage gate A-frags once (shared by all 4 waves)
  for (int i = threadIdx.x; i < 640; i += 256)
    ((float4*)smem)[i] = ((const float4*)fragsG)[i];

  const int tid  = threadIdx.x;
  const int lane = tid & 63;
  const int wv   = tid >> 6;
  const int m = lane & 15, q = lane >> 4;

  unsigned char* Zb = smem + 10240 + wv * 2560;   // bf16 [16][40]
  float*         Cw = (float*)(Zb + 1280);        // f32  [16][20]

  // lane-constant staging offsets (lane L carries floats 4L..4L+3; 5 lanes/row)
  const int m0 = lane / 5, j0 = lane - m0 * 5;
  const int l1 = 64 + lane;
  const int m1 = l1 / 5, j1 = l1 - m1 * 5;        // tail part (lanes < 16)
  const int zA = m0 * 80 + 8 * j0;                // Z byte offset (x); h at +40
  const int zB = m1 * 80 + 8 * j1;

  floatx4 biasr[5];
#pragma unroll
  for (int t = 0; t < 5; ++t) {
    float4 b4 = bias4[q * 5 + t];
    biasr[t] = (floatx4){b4.x, b4.y, b4.z, b4.w};
  }
  short8 afL0 = *(const short8*)(fragsL + (size_t)lane * 8);
  short8 afL1 = *(const short8*)(fragsL + (size_t)(64 + lane) * 8);

  __syncthreads();   // frag staging done — only barrier in the kernel

  const short8* aG = (const short8*)smem;
  float* outh = out;
  float* outc = out + (size_t)B * UNITS;

  const long stride = 64L * (long)gridDim.x;

  auto rbof = [&](long b) {
    long r = b + wv * 16;
    if (r + 16 > (long)B) r = (long)B - 16;   // duplicate-row stores are benign
    if (r < 0) r = 0;
    return r;
  };

#define LOADSET(rb, xa, ha, ca, xb, hb, cb) {                        \
    const float4* xp = (const float4*)(x + (rb) * 20);               \
    const float4* hp = (const float4*)(h + (rb) * 20);               \
    const float4* cp = (const float4*)(c + (rb) * 20);               \
    xa = xp[lane]; ha = hp[lane]; ca = cp[lane];                     \
    if (lane < 16) { xb = xp[64 + lane]; hb = hp[64 + lane]; cb = cp[64 + lane]; } }

#define STAGESET(xa, ha, ca, xb, hb, cb) {                           \
    u32x2 w;                                                         \
    w[0] = cvtpk(xa.x, xa.y); w[1] = cvtpk(xa.z, xa.w);              \
    *(u32x2*)(Zb + zA) = w;                                          \
    w[0] = cvtpk(ha.x, ha.y); w[1] = cvtpk(ha.z, ha.w);              \
    *(u32x2*)(Zb + zA + 40) = w;                                     \
    *(float4*)((unsigned char*)Cw + lane * 16) = ca;                 \
    if (lane < 16) {                                                 \
      w[0] = cvtpk(xb.x, xb.y); w[1] = cvtpk(xb.z, xb.w);            \
      *(u32x2*)(Zb + zB) = w;                                        \
      w[0] = cvtpk(hb.x, hb.y); w[1] = cvtpk(hb.z, hb.w);            \
      *(u32x2*)(Zb + zB + 40) = w;                                   \
      *(float4*)((unsigned char*)Cw + 1024 + lane * 16) = cb; } }

  // pipeline registers: set0 / set1
  float4 x0, h0, c0, x1, h1, c1;
  float4 x0b = make_float4(0, 0, 0, 0), h0b = x0b, c0b = x0b;
  float4 x1b = x0b, h1b = x0b, c1b = x0b;
  x0 = x0b; h0 = x0b; c0 = x0b; x1 = x0b; h1 = x0b; c1 = x0b;

  long bA = (long)blockIdx.x * 64;       // pass being consumed
  long rbA = rbof(bA);
  LOADSET(rbA, x0, h0, c0, x0b, h0b, c0b);
  long bB = bA + stride;                 // next pass
  bool mB = bB < (long)B;
  long rbB = rbA;
  if (mB) { rbB = rbof(bB); LOADSET(rbB, x1, h1, c1, x1b, h1b, c1b); }

  // consume pass (bA) from SET; refill SET with pass bA+2*stride; rotate.
#define PASS(xa, ha, ca, xb, hb, cb) {                                        \
    STAGESET(xa, ha, ca, xb, hb, cb);                                         \
    short8 bfr0 = *(const short8*)(Zb + m * 80 + q * 16);                     \
    short8 bfr1 = (short8){0, 0, 0, 0, 0, 0, 0, 0};                           \
    if (q == 0) bfr1 = *(const short8*)(Zb + m * 80 + 64);                    \
    float cvv[5];                                                             \
    _Pragma("unroll") for (int t = 0; t < 5; ++t) cvv[t] = Cw[m * 20 + q * 5 + t]; \
    long b2 = bA + 2 * stride; bool m2 = b2 < (long)B; long rb2 = rbA;        \
    if (m2) { rb2 = rbof(b2); LOADSET(rb2, xa, ha, ca, xb, hb, cb); }         \
    floatx4 acc[5];                                                           \
    _Pragma("unroll") for (int t = 0; t < 5; ++t) {                           \
      acc[t] = __builtin_amdgcn_mfma_f32_16x16x32_bf16(aG[(t * 2 + 0) * 64 + lane], bfr0, biasr[t], 0, 0, 0); \
      acc[t] = __builtin_amdgcn_mfma_f32_16x16x32_bf16(aG[(t * 2 + 1) * 64 + lane], bfr1, acc[t], 0, 0, 0); } \
    float cn[5], hl[5];                                                       \
    _Pragma("unroll") for (int t = 0; t < 5; ++t) {                           \
      float ig = sigmoidf_fast(acc[t][0]);                                    \
      float fg = sigmoidf_fast(acc[t][1]);                                    \
      float gg = tanhf_fast(acc[t][2]);                                       \
      float og = sigmoidf_fast(acc[t][3]);                                    \
      float cnv = fg * cvv[t] + ig * gg;                                      \
      cn[t] = cnv; hl[t] = og * tanhf_fast(cnv); }                            \
    u32x4 pl = {cvtpk(hl[0], hl[1]), cvtpk(hl[2], hl[3]), cvtpk(hl[4], 0.0f), 0u}; \
    short8 bl = __builtin_bit_cast(short8, pl);                               \
    floatx4 z4 = {0.f, 0.f, 0.f, 0.f};                                        \
    floatx4 accL0 = __builtin_amdgcn_mfma_f32_16x16x32_bf16(afL0, bl, z4, 0, 0, 0); \
    floatx4 accL1 = __builtin_amdgcn_mfma_f32_16x16x32_bf16(afL1, bl, z4, 0, 0, 0); \
    {                                                                         \
      long r20 = (rbA + m) * 20;                                              \
      float* co = outc + r20 + q * 5;                                         \
      co[0] = cn[0]; co[1] = cn[1]; co[2] = cn[2]; co[3] = cn[3]; co[4] = cn[4]; \
      float4 hv;                                                              \
      hv.x = tanhf_fast(accL0[0]); hv.y = tanhf_fast(accL0[1]);               \
      hv.z = tanhf_fast(accL0[2]); hv.w = tanhf_fast(accL0[3]);               \
      *(float4*)(outh + r20 + q * 4) = hv;                                    \
      if (q == 0) {                                                           \
        float4 hw;                                                            \
        hw.x = tanhf_fast(accL1[0]); hw.y = tanhf_fast(accL1[1]);             \
        hw.z = tanhf_fast(accL1[2]); hw.w = tanhf_fast(accL1[3]);             \
        *(float4*)(outh + r20 + 16) = hw; }                                   \
    }                                                                         \
    bool cont = mB;                                                           \
    bA = bB; rbA = rbB; bB = b2; rbB = rb2; mB = m2;                          \
    if (!cont) break; }

  while (true) {
    PASS(x0, h0, c0, x0b, h0b, c0b)
    PASS(x1, h1, c1, x1b, h1b, c1b)
  }

#undef PASS
#undef STAGESET
#undef LOADSET
}

extern "C" void kernel_launch(void* const* d_in, const int* in_sizes, int n_in,
                              void* d_out, int out_size, void* d_ws, size_t ws_size,
                              hipStream_t stream) {
  const float* x     = (const float*)d_in[0];
  const float* h     = (const float*)d_in[1];
  const float* c     = (const float*)d_in[2];
  const float* W_ih  = (const float*)d_in[3];
  const float* W_hh  = (const float*)d_in[4];
  const float* b_ih  = (const float*)d_in[5];
  const float* b_hh  = (const float*)d_in[6];
  const float* W_lat = (const float*)d_in[7];
  float* out = (float*)d_out;

  u16*    fragsG = (u16*)d_ws;                         // 10*64*8*2 = 10240 B
  u16*    fragsL = (u16*)((char*)d_ws + 10240);        //  2*64*8*2 =  2048 B
  float4* bias4  = (float4*)((char*)d_ws + 12288);     //  20*16    =   320 B

  int B = in_sizes[0] / UNITS;
  prep_kernel<<<1, 256, 0, stream>>>(W_ih, W_hh, b_ih, b_hh, W_lat, fragsG, fragsL, bias4);
  long chunks = ((long)B + 63) / 64;
  int grid = (int)(chunks < 2048 ? chunks : 2048);
  stn_main<<<grid, 256, 0, stream>>>(x, h, c, fragsG, fragsL, bias4, out, B);
}

// Round 8
// 213.987 us; speedup vs baseline: 1.0175x; 1.0175x over previous
//
#include <hip/hip_runtime.h>

#define UNITS 20

typedef __attribute__((ext_vector_type(8))) short short8;
typedef __attribute__((ext_vector_type(4))) float floatx4;
typedef __attribute__((ext_vector_type(2))) unsigned int u32x2;
typedef __attribute__((ext_vector_type(4))) unsigned int u32x4;
typedef unsigned int u32;
typedef unsigned short u16;

__device__ __forceinline__ float rcpf_fast(float x) { return __builtin_amdgcn_rcpf(x); }
__device__ __forceinline__ float sigmoidf_fast(float x) { return rcpf_fast(1.0f + __expf(-x)); }
__device__ __forceinline__ float tanhf_fast(float x) { return 1.0f - 2.0f * rcpf_fast(1.0f + __expf(2.0f * x)); }

__device__ __forceinline__ u32 f2bf(float f) {
  u32 u = __builtin_bit_cast(u32, f);
  u += 0x7fffu + ((u >> 16) & 1u);   // RNE
  return u >> 16;
}
// packed f32->bf16 (RNE): lo -> D[15:0], hi -> D[31:16]
__device__ __forceinline__ u32 cvtpk(float lo, float hi) {
  u32 r;
  asm("v_cvt_pk_bf16_f32 %0, %1, %2" : "=v"(r) : "v"(lo), "v"(hi));
  return r;
}

// ---------------------------------------------------------------------------
// Prep (unchanged): pack A-operand fragments.
//  gates^T = Wcat . Z^T, permuted rows -> acc[t][reg] = gate[reg*20+q*5+t].
//  lateral^T with sigma-permuted K (k=q*8+j holds W_lat col q*5+j, j<5) so
//  the lateral B-operand is lane-local in the main kernel.
// ---------------------------------------------------------------------------
__global__ void prep_kernel(const float* __restrict__ W_ih, const float* __restrict__ W_hh,
                            const float* __restrict__ b_ih, const float* __restrict__ b_hh,
                            const float* __restrict__ W_lat,
                            u16* __restrict__ fragsG, u16* __restrict__ fragsL,
                            float4* __restrict__ bias4) {
  int tid = threadIdx.x;
  for (int e = tid; e < 768; e += 256) {   // 10 gate frags + 2 lateral frags
    int fi = e >> 6, lane = e & 63;
    int r = lane & 15, q = lane >> 4;
    short8 v8;
    if (fi < 10) {
      int t = fi >> 1, cc = fi & 1;
      int gr = (r & 3) * 20 + (r >> 2) * 5 + t;   // permuted gate row
#pragma unroll
      for (int j = 0; j < 8; ++j) {
        int k = cc * 32 + q * 8 + j;
        float v = 0.0f;
        if (k < 20) v = W_ih[gr * UNITS + k];
        else if (k < 40) v = W_hh[gr * UNITS + (k - 20)];
        v8[j] = (short)f2bf(v);
      }
      *(short8*)(fragsG + (size_t)e * 8) = v8;
    } else {
      int t = fi - 10;
      int vr = t * 16 + r;
#pragma unroll
      for (int j = 0; j < 8; ++j) {
        float v = (vr < 20 && j < 5) ? W_lat[vr * UNITS + q * 5 + j] : 0.0f;
        v8[j] = (short)f2bf(v);
      }
      *(short8*)(fragsL + (size_t)(t * 64 + lane) * 8) = v8;
    }
  }
  if (tid < 20)
    bias4[tid] = make_float4(b_ih[tid] + b_hh[tid],
                             b_ih[20 + tid] + b_hh[20 + tid],
                             b_ih[40 + tid] + b_hh[40 + tid],
                             b_ih[60 + tid] + b_hh[60 + tid]);
}

// ---------------------------------------------------------------------------
// Main: depth-2 read pipeline + amplification-proof burst stores.
// vs round 7 (which failed correctness): outputs get their OWN wave-private
// LDS region (no reuse of the input staging bytes -> no TBAA-legal
// reordering of next-pass u32x2 input writes across float4 output reads),
// and compiler memory fences (asm "":::"memory", zero instructions) pin the
// LDS write->read boundaries. Same-wave LDS ops are in-order in HW; the
// fences only stop COMPILER motion.
// LDS: [0,10240) gate A-frags; [10240,20480) per-wave input staging
// (bf16 z + f32 c); [20480,30720) per-wave output staging (f32 h' + c').
// ---------------------------------------------------------------------------
__global__ __launch_bounds__(256, 4) void stn_main(
    const float* __restrict__ x, const float* __restrict__ h, const float* __restrict__ c,
    const u16* __restrict__ fragsG, const u16* __restrict__ fragsL,
    const float4* __restrict__ bias4, float* __restrict__ out, int B) {
  __shared__ unsigned char smem[30720];

  // stage gate A-frags once (shared by all 4 waves)
  for (int i = threadIdx.x; i < 640; i += 256)
    ((float4*)smem)[i] = ((const float4*)fragsG)[i];

  const int tid  = threadIdx.x;
  const int lane = tid & 63;
  const int wv   = tid >> 6;
  const int m = lane & 15, q = lane >> 4;

  unsigned char* Zb = smem + 10240 + wv * 2560;   // input: bf16 [16][40]
  float*         Cw = (float*)(Zb + 1280);        // input: f32  [16][20]
  unsigned char* Zo = smem + 20480 + wv * 2560;   // output staging
  float*         Hs = (float*)Zo;                 // f32 [16][20] h'
  float*         Cs = (float*)(Zo + 1280);        // f32 [16][20] c'

  // lane-constant staging offsets (lane L carries floats 4L..4L+3; 5 lanes/row)
  const int m0 = lane / 5, j0 = lane - m0 * 5;
  const int l1 = 64 + lane;
  const int m1 = l1 / 5, j1 = l1 - m1 * 5;        // tail part (lanes < 16)
  const int zA = m0 * 80 + 8 * j0;                // Z byte offset (x); h at +40
  const int zB = m1 * 80 + 8 * j1;

  floatx4 biasr[5];
#pragma unroll
  for (int t = 0; t < 5; ++t) {
    float4 b4 = bias4[q * 5 + t];
    biasr[t] = (floatx4){b4.x, b4.y, b4.z, b4.w};
  }
  short8 afL0 = *(const short8*)(fragsL + (size_t)lane * 8);
  short8 afL1 = *(const short8*)(fragsL + (size_t)(64 + lane) * 8);

  __syncthreads();   // frag staging done — only barrier in the kernel

  const short8* aG = (const short8*)smem;
  float* outh = out;
  float* outc = out + (size_t)B * UNITS;

  const long stride = 64L * (long)gridDim.x;

  auto rbof = [&](long b) {
    long r = b + wv * 16;
    if (r + 16 > (long)B) r = (long)B - 16;   // duplicate-row stores are benign
    if (r < 0) r = 0;
    return r;
  };

#define LOADSET(rb, xa, ha, ca, xb, hb, cb) {                        \
    const float4* xp = (const float4*)(x + (rb) * 20);               \
    const float4* hp = (const float4*)(h + (rb) * 20);               \
    const float4* cp = (const float4*)(c + (rb) * 20);               \
    xa = xp[lane]; ha = hp[lane]; ca = cp[lane];                     \
    if (lane < 16) { xb = xp[64 + lane]; hb = hp[64 + lane]; cb = cp[64 + lane]; } }

#define STAGESET(xa, ha, ca, xb, hb, cb) {                           \
    u32x2 w;                                                         \
    w[0] = cvtpk(xa.x, xa.y); w[1] = cvtpk(xa.z, xa.w);              \
    *(u32x2*)(Zb + zA) = w;                                          \
    w[0] = cvtpk(ha.x, ha.y); w[1] = cvtpk(ha.z, ha.w);              \
    *(u32x2*)(Zb + zA + 40) = w;                                     \
    *(float4*)((unsigned char*)Cw + lane * 16) = ca;                 \
    if (lane < 16) {                                                 \
      w[0] = cvtpk(xb.x, xb.y); w[1] = cvtpk(xb.z, xb.w);            \
      *(u32x2*)(Zb + zB) = w;                                        \
      w[0] = cvtpk(hb.x, hb.y); w[1] = cvtpk(hb.z, hb.w);            \
      *(u32x2*)(Zb + zB + 40) = w;                                   \
      *(float4*)((unsigned char*)Cw + 1024 + lane * 16) = cb; } }

  // pipeline registers: set0 / set1
  float4 x0, h0, c0, x1, h1, c1;
  float4 x0b = make_float4(0, 0, 0, 0), h0b = x0b, c0b = x0b;
  float4 x1b = x0b, h1b = x0b, c1b = x0b;
  x0 = x0b; h0 = x0b; c0 = x0b; x1 = x0b; h1 = x0b; c1 = x0b;

  long bA = (long)blockIdx.x * 64;       // pass being consumed
  long rbA = rbof(bA);
  LOADSET(rbA, x0, h0, c0, x0b, h0b, c0b);
  long bB = bA + stride;                 // next pass
  bool mB = bB < (long)B;
  long rbB = rbA;
  if (mB) { rbB = rbof(bB); LOADSET(rbB, x1, h1, c1, x1b, h1b, c1b); }

  // consume pass (bA) from SET; refill SET with pass bA+2*stride; rotate.
#define PASS(xa, ha, ca, xb, hb, cb) {                                        \
    STAGESET(xa, ha, ca, xb, hb, cb);                                         \
    asm volatile("" ::: "memory");      /* input W -> frag R boundary */      \
    short8 bfr0 = *(const short8*)(Zb + m * 80 + q * 16);                     \
    short8 bfr1 = (short8){0, 0, 0, 0, 0, 0, 0, 0};                           \
    if (q == 0) bfr1 = *(const short8*)(Zb + m * 80 + 64);                    \
    float cvv[5];                                                             \
    _Pragma("unroll") for (int t = 0; t < 5; ++t) cvv[t] = Cw[m * 20 + q * 5 + t]; \
    long b2 = bA + 2 * stride; bool m2 = b2 < (long)B; long rb2 = rbA;        \
    if (m2) { rb2 = rbof(b2); LOADSET(rb2, xa, ha, ca, xb, hb, cb); }         \
    floatx4 acc[5];                                                           \
    _Pragma("unroll") for (int t = 0; t < 5; ++t) {                           \
      acc[t] = __builtin_amdgcn_mfma_f32_16x16x32_bf16(aG[(t * 2 + 0) * 64 + lane], bfr0, biasr[t], 0, 0, 0); \
      acc[t] = __builtin_amdgcn_mfma_f32_16x16x32_bf16(aG[(t * 2 + 1) * 64 + lane], bfr1, acc[t], 0, 0, 0); } \
    float cn[5], hl[5];                                                       \
    _Pragma("unroll") for (int t = 0; t < 5; ++t) {                           \
      float ig = sigmoidf_fast(acc[t][0]);                                    \
      float fg = sigmoidf_fast(acc[t][1]);                                    \
      float gg = tanhf_fast(acc[t][2]);                                       \
      float og = sigmoidf_fast(acc[t][3]);                                    \
      float cnv = fg * cvv[t] + ig * gg;                                      \
      cn[t] = cnv; hl[t] = og * tanhf_fast(cnv); }                            \
    u32x4 pl = {cvtpk(hl[0], hl[1]), cvtpk(hl[2], hl[3]), cvtpk(hl[4], 0.0f), 0u}; \
    short8 bl = __builtin_bit_cast(short8, pl);                               \
    floatx4 z4 = {0.f, 0.f, 0.f, 0.f};                                        \
    floatx4 accL0 = __builtin_amdgcn_mfma_f32_16x16x32_bf16(afL0, bl, z4, 0, 0, 0); \
    floatx4 accL1 = __builtin_amdgcn_mfma_f32_16x16x32_bf16(afL1, bl, z4, 0, 0, 0); \
    /* ---- stage outputs into the DEDICATED wave-private region ---- */      \
    {                                                                         \
      float4 hv;                                                              \
      hv.x = tanhf_fast(accL0[0]); hv.y = tanhf_fast(accL0[1]);               \
      hv.z = tanhf_fast(accL0[2]); hv.w = tanhf_fast(accL0[3]);               \
      *(float4*)(Hs + m * 20 + q * 4) = hv;            /* units q*4..q*4+3 */ \
      if (q == 0) {                                                           \
        float4 hw;                                                            \
        hw.x = tanhf_fast(accL1[0]); hw.y = tanhf_fast(accL1[1]);             \
        hw.z = tanhf_fast(accL1[2]); hw.w = tanhf_fast(accL1[3]);             \
        *(float4*)(Hs + m * 20 + 16) = hw;             /* units 16..19 */     \
      }                                                                       \
      float* cs = Cs + m * 20 + q * 5;                                        \
      cs[0] = cn[0]; cs[1] = cn[1]; cs[2] = cn[2]; cs[3] = cn[3]; cs[4] = cn[4]; \
      asm volatile("" ::: "memory");    /* output W -> burst R boundary */    \
      /* ---- contiguous wave-level burst stores (full-line coverage) ---- */ \
      long rb5 = rbA * 5;                                                     \
      float4* oh4 = (float4*)outh + rb5;                                      \
      float4* oc4 = (float4*)outc + rb5;                                      \
      oh4[lane] = ((const float4*)Hs)[lane];                                  \
      oc4[lane] = ((const float4*)Cs)[lane];                                  \
      if (lane < 16) {                                                        \
        oh4[64 + lane] = ((const float4*)Hs)[64 + lane];                      \
        oc4[64 + lane] = ((const float4*)Cs)[64 + lane];                      \
      }                                                                       \
      asm volatile("" ::: "memory");    /* burst R -> next-pass W boundary */ \
    }                                                                         \
    bool cont = mB;                                                           \
    bA = bB; rbA = rbB; bB = b2; rbB = rb2; mB = m2;                          \
    if (!cont) break; }

  while (true) {
    PASS(x0, h0, c0, x0b, h0b, c0b)
    PASS(x1, h1, c1, x1b, h1b, c1b)
  }

#undef PASS
#undef STAGESET
#undef LOADSET
}

extern "C" void kernel_launch(void* const* d_in, const int* in_sizes, int n_in,
                              void* d_out, int out_size, void* d_ws, size_t ws_size,
                              hipStream_t stream) {
  const float* x     = (const float*)d_in[0];
  const float* h     = (const float*)d_in[1];
  const float* c     = (const float*)d_in[2];
  const float* W_ih  = (const float*)d_in[3];
  const float* W_hh  = (const float*)d_in[4];
  const float* b_ih  = (const float*)d_in[5];
  const float* b_hh  = (const float*)d_in[6];
  const float* W_lat = (const float*)d_in[7];
  float* out = (float*)d_out;

  u16*    fragsG = (u16*)d_ws;                         // 10*64*8*2 = 10240 B
  u16*    fragsL = (u16*)((char*)d_ws + 10240);        //  2*64*8*2 =  2048 B
  float4* bias4  = (float4*)((char*)d_ws + 12288);     //  20*16    =   320 B

  int B = in_sizes[0] / UNITS;
  prep_kernel<<<1, 256, 0, stream>>>(W_ih, W_hh, b_ih, b_hh, W_lat, fragsG, fragsL, bias4);
  long chunks = ((long)B + 63) / 64;
  int grid = (int)(chunks < 2048 ? chunks : 2048);
  stn_main<<<grid, 256, 0, stream>>>(x, h, c, fragsG, fragsL, bias4, out, B);
}

// Round 10
// 207.461 us; speedup vs baseline: 1.0495x; 1.0315x over previous
//
#include <hip/hip_runtime.h>

#define UNITS 20

typedef __attribute__((ext_vector_type(8))) short short8;
typedef __attribute__((ext_vector_type(4))) float floatx4;
typedef __attribute__((ext_vector_type(4))) unsigned int u32x4;
typedef unsigned int u32;
typedef unsigned short u16;

__device__ __forceinline__ float rcpf_fast(float x) { return __builtin_amdgcn_rcpf(x); }
__device__ __forceinline__ float sigmoidf_fast(float x) { return rcpf_fast(1.0f + __expf(-x)); }
__device__ __forceinline__ float tanhf_fast(float x) { return 1.0f - 2.0f * rcpf_fast(1.0f + __expf(2.0f * x)); }

__device__ __forceinline__ u32 f2bf(float f) {
  u32 u = __builtin_bit_cast(u32, f);
  u += 0x7fffu + ((u >> 16) & 1u);   // RNE
  return u >> 16;
}
// packed f32->bf16 (RNE): lo -> D[15:0], hi -> D[31:16]
__device__ __forceinline__ u32 cvtpk(float lo, float hi) {
  u32 r;
  asm("v_cvt_pk_bf16_f32 %0, %1, %2" : "=v"(r) : "v"(lo), "v"(hi));
  return r;
}

// direct global->LDS (no VGPR round-trip). LDS dest is wave-uniform base;
// HW writes base + lane*size. Global src is per-lane.
typedef __attribute__((address_space(1))) unsigned char u8_g;
typedef __attribute__((address_space(3))) unsigned char u8_l;
__device__ __forceinline__ void gl_lds16(const float* g, unsigned char* s) {
  __builtin_amdgcn_global_load_lds((const u8_g*)(const void*)g, (u8_l*)(void*)s, 16, 0, 0);
}
__device__ __forceinline__ void gl_lds4(const float* g, unsigned char* s) {
  __builtin_amdgcn_global_load_lds((const u8_g*)(const void*)g, (u8_l*)(void*)s, 4, 0, 0);
}

// ---------------------------------------------------------------------------
// Prep (unchanged): pack A-operand fragments.
// ---------------------------------------------------------------------------
__global__ void prep_kernel(const float* __restrict__ W_ih, const float* __restrict__ W_hh,
                            const float* __restrict__ b_ih, const float* __restrict__ b_hh,
                            const float* __restrict__ W_lat,
                            u16* __restrict__ fragsG, u16* __restrict__ fragsL,
                            float4* __restrict__ bias4) {
  int tid = threadIdx.x;
  for (int e = tid; e < 768; e += 256) {   // 10 gate frags + 2 lateral frags
    int fi = e >> 6, lane = e & 63;
    int r = lane & 15, q = lane >> 4;
    short8 v8;
    if (fi < 10) {
      int t = fi >> 1, cc = fi & 1;
      int gr = (r & 3) * 20 + (r >> 2) * 5 + t;   // permuted gate row
#pragma unroll
      for (int j = 0; j < 8; ++j) {
        int k = cc * 32 + q * 8 + j;
        float v = 0.0f;
        if (k < 20) v = W_ih[gr * UNITS + k];
        else if (k < 40) v = W_hh[gr * UNITS + (k - 20)];
        v8[j] = (short)f2bf(v);
      }
      *(short8*)(fragsG + (size_t)e * 8) = v8;
    } else {
      int t = fi - 10;
      int vr = t * 16 + r;
#pragma unroll
      for (int j = 0; j < 8; ++j) {
        float v = (vr < 20 && j < 5) ? W_lat[vr * UNITS + q * 5 + j] : 0.0f;
        v8[j] = (short)f2bf(v);
      }
      *(short8*)(fragsL + (size_t)(t * 64 + lane) * 8) = v8;
    }
  }
  if (tid < 20)
    bias4[tid] = make_float4(b_ih[tid] + b_hh[tid],
                             b_ih[20 + tid] + b_hh[20 + tid],
                             b_ih[40 + tid] + b_hh[40 + tid],
                             b_ih[60 + tid] + b_hh[60 + tid]);
}

// ---------------------------------------------------------------------------
// Main: 3-stage LDS ring fed by global_load_lds, counted-vmcnt pipeline with
// TWO passes of x/h loads permanently in flight (never drains to 0), zero
// staging VGPRs (no spill possible). c in/out and h' out use the per-lane
// shapes proven byte-clean in r1/r2. bf16 conversion happens at frag-read.
// LDS: [0,10240) gate A-frags; per wave at 10240+wv*7680: 3 stages x
// (x 1280B f32 | h 1280B f32).
// vmcnt waits (10/16/20) are safe for ANY compiler merge of the scalar
// c-ops: N <= min over CL in 2..5, ST in 4..7 of ops-newer-than-GL batch
// (steady: 2CL+2ST+8 >= 20; p0: CL+8 >= 10; p1: 2CL+ST+8 >= 16).
// ---------------------------------------------------------------------------
__global__ __launch_bounds__(256, 2) void stn_main(
    const float* __restrict__ x, const float* __restrict__ h, const float* __restrict__ c,
    const u16* __restrict__ fragsG, const u16* __restrict__ fragsL,
    const float4* __restrict__ bias4, float* __restrict__ out, int B) {
  __shared__ unsigned char smem[40960];

  for (int i = threadIdx.x; i < 640; i += 256)
    ((float4*)smem)[i] = ((const float4*)fragsG)[i];

  const int tid  = threadIdx.x;
  const int lane = tid & 63;
  const int wv   = tid >> 6;
  const int m = lane & 15, q = lane >> 4;

  unsigned char* SBASE = smem + 10240 + wv * 7680;   // 3 stages x 2560 B

  floatx4 biasr[5];
#pragma unroll
  for (int t = 0; t < 5; ++t) {
    float4 b4 = bias4[q * 5 + t];
    biasr[t] = (floatx4){b4.x, b4.y, b4.z, b4.w};
  }
  short8 afL0 = *(const short8*)(fragsL + (size_t)lane * 8);
  short8 afL1 = *(const short8*)(fragsL + (size_t)(64 + lane) * 8);

  __syncthreads();   // gate-frag staging done — only barrier in the kernel

  const short8* aG = (const short8*)smem;
  float* outh = out;
  float* outc = out + (size_t)B * UNITS;

  const long stride = 64L * (long)gridDim.x;
  long bA = (long)blockIdx.x * 64;

  auto rbof = [&](long b) {
    long r = b + wv * 16;
    if (r + 16 > (long)B) r = (long)B - 16;   // duplicate-row stores are benign
    if (r < 0) r = 0;
    return r;
  };

// issue x/h loads for rows rbof(bb) into stage SGL (4 VMEM, all full-wave)
#define GL(SGL, bb) { \
    long rb2_ = rbof(bb); \
    const float* xs_ = x + rb2_ * 20; \
    const float* hs_ = h + rb2_ * 20; \
    unsigned char* d_ = SBASE + (SGL); \
    gl_lds16(xs_ + lane * 4, d_); \
    gl_lds4 (xs_ + 256 + lane, d_ + 1024); \
    gl_lds16(hs_ + lane * 4, d_ + 1280); \
    gl_lds4 (hs_ + 256 + lane, d_ + 2304); \
  }

// one pass: consume stage SCUR + c-regs CC; issue gl for p+2 into SGL and
// c-loads for p+1 into CF. KW = counted vmcnt (string).
#define PASS(SCUR, SGL, KW, CC, CF) { \
    GL(SGL, bA + 2 * stride); \
    asm volatile("s_waitcnt vmcnt(" KW ")" ::: "memory"); \
    __builtin_amdgcn_sched_barrier(0); \
    const unsigned char* X_ = SBASE + (SCUR); \
    const unsigned char* H_ = X_ + 1280; \
    const int mo_ = m * 80; \
    const unsigned char* pA_ = (q == 0) ? X_ + mo_      : (q == 1) ? X_ + mo_ + 32 \
                             : (q == 2) ? X_ + mo_ + 64 : H_ + mo_ + 16; \
    const unsigned char* pB_ = (q == 0) ? X_ + mo_ + 16 : (q == 1) ? X_ + mo_ + 48 \
                             : (q == 2) ? H_ + mo_      : H_ + mo_ + 32; \
    float4 fa_ = *(const float4*)pA_; \
    float4 fb_ = *(const float4*)pB_; \
    u32x4 w0_ = {cvtpk(fa_.x, fa_.y), cvtpk(fa_.z, fa_.w), cvtpk(fb_.x, fb_.y), cvtpk(fb_.z, fb_.w)}; \
    short8 bfr0 = __builtin_bit_cast(short8, w0_); \
    short8 bfr1 = (short8){0, 0, 0, 0, 0, 0, 0, 0}; \
    if (q == 0) { \
      float4 ga_ = *(const float4*)(H_ + mo_ + 48); \
      float4 gb_ = *(const float4*)(H_ + mo_ + 64); \
      u32x4 w1_ = {cvtpk(ga_.x, ga_.y), cvtpk(ga_.z, ga_.w), cvtpk(gb_.x, gb_.y), cvtpk(gb_.z, gb_.w)}; \
      bfr1 = __builtin_bit_cast(short8, w1_); \
    } \
    { long rb1_ = rbof(bA + stride); \
      const float* cp_ = c + (rb1_ + m) * 20 + q * 5; \
      _Pragma("unroll") for (int t = 0; t < 5; ++t) CF[t] = cp_[t]; } \
    floatx4 acc[5]; \
    _Pragma("unroll") for (int t = 0; t < 5; ++t) { \
      acc[t] = __builtin_amdgcn_mfma_f32_16x16x32_bf16(aG[(t * 2 + 0) * 64 + lane], bfr0, biasr[t], 0, 0, 0); \
      acc[t] = __builtin_amdgcn_mfma_f32_16x16x32_bf16(aG[(t * 2 + 1) * 64 + lane], bfr1, acc[t], 0, 0, 0); } \
    float cn_[5], hl_[5]; \
    _Pragma("unroll") for (int t = 0; t < 5; ++t) { \
      float ig = sigmoidf_fast(acc[t][0]); \
      float fg = sigmoidf_fast(acc[t][1]); \
      float gg = tanhf_fast(acc[t][2]); \
      float og = sigmoidf_fast(acc[t][3]); \
      float cnv = fg * CC[t] + ig * gg; \
      cn_[t] = cnv; hl_[t] = og * tanhf_fast(cnv); } \
    u32x4 pl_ = {cvtpk(hl_[0], hl_[1]), cvtpk(hl_[2], hl_[3]), cvtpk(hl_[4], 0.0f), 0u}; \
    short8 bl_ = __builtin_bit_cast(short8, pl_); \
    floatx4 z4_ = {0.f, 0.f, 0.f, 0.f}; \
    floatx4 aL0 = __builtin_amdgcn_mfma_f32_16x16x32_bf16(afL0, bl_, z4_, 0, 0, 0); \
    floatx4 aL1 = __builtin_amdgcn_mfma_f32_16x16x32_bf16(afL1, bl_, z4_, 0, 0, 0); \
    { long r20_ = (rbof(bA) + m) * 20; \
      float* co_ = outc + r20_ + q * 5; \
      co_[0] = cn_[0]; co_[1] = cn_[1]; co_[2] = cn_[2]; co_[3] = cn_[3]; co_[4] = cn_[4]; \
      float4 hv_; \
      hv_.x = tanhf_fast(aL0[0]); hv_.y = tanhf_fast(aL0[1]); \
      hv_.z = tanhf_fast(aL0[2]); hv_.w = tanhf_fast(aL0[3]); \
      *(float4*)(outh + r20_ + q * 4) = hv_; \
      if (q == 0) { \
        float4 hw_; \
        hw_.x = tanhf_fast(aL1[0]); hw_.y = tanhf_fast(aL1[1]); \
        hw_.z = tanhf_fast(aL1[2]); hw_.w = tanhf_fast(aL1[3]); \
        *(float4*)(outh + r20_ + 16) = hw_; } } \
    bool more_ = (bA + stride) < (long)B; \
    bA += stride; \
    if (!more_) break; \
  }

  float cva[5], cvb[5];

  // prologue: gl(p0)->stage0, gl(p1)->stage1, c(p0)->cva
  GL(0, bA);
  GL(2560, bA + stride);
  { long rb0_ = rbof(bA);
    const float* cp_ = c + (rb0_ + m) * 20 + q * 5;
#pragma unroll
    for (int t = 0; t < 5; ++t) cva[t] = cp_[t]; }

  do {
    PASS(0,    5120, "10", cva, cvb)   // p0
    PASS(2560, 0,    "16", cvb, cva)   // p1
    while (true) {
      PASS(5120, 2560, "20", cva, cvb) // p2 (steady)
      PASS(0,    5120, "20", cvb, cva) // p3
      PASS(2560, 0,    "20", cva, cvb) // p4
      PASS(5120, 2560, "20", cvb, cva) // p5
      PASS(0,    5120, "20", cva, cvb) // p6
      PASS(2560, 0,    "20", cvb, cva) // p7
    }
  } while (0);

#undef PASS
#undef GL
}

extern "C" void kernel_launch(void* const* d_in, const int* in_sizes, int n_in,
                              void* d_out, int out_size, void* d_ws, size_t ws_size,
                              hipStream_t stream) {
  const float* x     = (const float*)d_in[0];
  const float* h     = (const float*)d_in[1];
  const float* c     = (const float*)d_in[2];
  const float* W_ih  = (const float*)d_in[3];
  const float* W_hh  = (const float*)d_in[4];
  const float* b_ih  = (const float*)d_in[5];
  const float* b_hh  = (const float*)d_in[6];
  const float* W_lat = (const float*)d_in[7];
  float* out = (float*)d_out;

  u16*    fragsG = (u16*)d_ws;                         // 10*64*8*2 = 10240 B
  u16*    fragsL = (u16*)((char*)d_ws + 10240);        //  2*64*8*2 =  2048 B
  float4* bias4  = (float4*)((char*)d_ws + 12288);     //  20*16    =   320 B

  int B = in_sizes[0] / UNITS;
  prep_kernel<<<1, 256, 0, stream>>>(W_ih, W_hh, b_ih, b_hh, W_lat, fragsG, fragsL, bias4);
  long chunks = ((long)B + 63) / 64;
  // 768 = 3 blocks/CU x 256 CU: full LDS-limited residency, no swap
  int grid = (int)(chunks < 768 ? chunks : 768);
  stn_main<<<grid, 256, 0, stream>>>(x, h, c, fragsG, fragsL, bias4, out, B);
}